// Round 3
// baseline (429.983 us; speedup 1.0000x reference)
//
#include <hip/hip_runtime.h>
#include <math.h>

#define NROWS 8192
#define NCOLS 8192
#define RB 64
#define CB 64
#define GRID 1024

// ---------------------------------------------------------------------------
// One fused kernel, one pass over X (268 MB -> HBM-bound, 43 us floor).
// Grid: 1024 WGs x 256 thr. WG w owns rows [(w>>3)*64,+64), cols [(w&7)*1024,+1024);
// each thread owns 4 consecutive cols (float4, fully coalesced).
//
// row_ids sorted -> row-block id is WG-uniform; rows processed in groups of 8
// with a uniform no-boundary fast path (8 back-to-back dwordx4 loads -> high
// memory-level parallelism; only ~63 boundaries exist across all 128 chunks).
// On a run boundary: flush register acc -> LDS (1 atomic/thread, since the 4
// cols nearly always share one col-block) -> 64 global atomics into acc_g.
//
// WGs 0/1 also build the row/col histograms + cumsums (32 KB of id reads,
// hidden under the X stream). The LAST WG to finish (global ticket) runs the
// 4096-cell 1->3->3->1 MLP + sigmoid epilogue -> no second kernel.
// ---------------------------------------------------------------------------
__global__ __launch_bounds__(256) void fused_kernel(
    const float* __restrict__ X,
    const int*   __restrict__ row_ids,
    const int*   __restrict__ col_ids,
    float*       __restrict__ acc_g,   // ws [4096], pre-zeroed
    float*       __restrict__ cnts,    // ws [128] fp32 counts
    int*         __restrict__ ticket,  // ws [1], pre-zeroed
    const float* __restrict__ W1, const float* __restrict__ b1,
    const float* __restrict__ W2, const float* __restrict__ b2,
    const float* __restrict__ W3, const float* __restrict__ b3,
    float*       __restrict__ out)
{
    __shared__ int   rids[64];
    __shared__ float lacc[64];
    __shared__ int   hist[64];
    __shared__ int   lastflag;

    const int tid = threadIdx.x;
    const int bx  = blockIdx.x & 7;
    const int by  = blockIdx.x >> 3;

    // ---- counts + cumsums (WGs 0,1; block-uniform branch) ----
    if (blockIdx.x < 2) {
        const int* ids = (blockIdx.x == 0) ? row_ids : col_ids;
        const int  n   = (blockIdx.x == 0) ? NROWS : NCOLS;
        if (tid < 64) hist[tid] = 0;
        __syncthreads();
        for (int i = tid; i < n; i += 256) atomicAdd(&hist[ids[i]], 1);
        __syncthreads();
        if (tid < 64) cnts[blockIdx.x * 64 + tid] = (float)hist[tid];
        if (tid == 0) {
            float* obase = out + RB * CB + blockIdx.x * (RB + 1);
            int c = 0;
            obase[0] = 0.0f;
            for (int i = 0; i < 64; ++i) { c += hist[i]; obase[i + 1] = (float)c; }
        }
        __syncthreads();
    }

    // ---- tile reduction ----
    if (tid < 64) { rids[tid] = row_ids[by * 64 + tid]; lacc[tid] = 0.0f; }
    __syncthreads();

    const int   c     = bx * 1024 + tid * 4;
    const int4  cb4   = *(const int4*)(col_ids + c);
    const bool  split = (cb4.x != cb4.w);        // 4 cols span >1 col-block (rare)
    const float* Xp   = X + (size_t)(by * 64) * NCOLS + c;

    float4 a  = make_float4(0.f, 0.f, 0.f, 0.f);
    int    cur = rids[0];

    auto FLUSH = [&](int blk) {                  // WG-uniform call sites only
        if (split) {
            atomicAdd(&lacc[cb4.x], a.x); atomicAdd(&lacc[cb4.y], a.y);
            atomicAdd(&lacc[cb4.z], a.z); atomicAdd(&lacc[cb4.w], a.w);
        } else {
            atomicAdd(&lacc[cb4.x], a.x + a.y + a.z + a.w);
        }
        __syncthreads();
        if (tid < 64) {
            const float v = lacc[tid];
            if (v != 0.0f) atomicAdd(&acc_g[blk * 64 + tid], v);
        }
        __syncthreads();
        if (tid < 64) lacc[tid] = 0.0f;
        __syncthreads();
        a = make_float4(0.f, 0.f, 0.f, 0.f);
    };

    #pragma unroll
    for (int g = 0; g < 8; ++g) {
        const int rb0 = rids[g * 8];
        if (rb0 != cur) { FLUSH(cur); cur = rb0; }        // WG-uniform
        if (rids[g * 8 + 7] == rb0) {
            // fast path: no boundary in this 8-row group -> 8 loads in flight
            #pragma unroll
            for (int j = 0; j < 8; ++j) {
                const float4 v = *(const float4*)(Xp + (size_t)(g * 8 + j) * NCOLS);
                a.x += v.x; a.y += v.y; a.z += v.z; a.w += v.w;
            }
        } else {
            for (int j = 0; j < 8; ++j) {
                const int rb = rids[g * 8 + j];
                if (rb != cur) { FLUSH(cur); cur = rb; }  // WG-uniform
                const float4 v = *(const float4*)(Xp + (size_t)(g * 8 + j) * NCOLS);
                a.x += v.x; a.y += v.y; a.z += v.z; a.w += v.w;
            }
        }
    }
    FLUSH(cur);

    // ---- completion ticket; last WG runs the MLP epilogue ----
    if (tid == 0) {
        __threadfence();
        lastflag = (atomicAdd(ticket, 1) == GRID - 1);
    }
    __syncthreads();
    if (lastflag) {
        __threadfence();   // acquire: all WGs' acc_g/cnts writes now visible
        float w1[3], bb1[3], w2[9], bb2[3], w3[3];
        #pragma unroll
        for (int i = 0; i < 3; ++i) { w1[i] = W1[i]; bb1[i] = b1[i]; bb2[i] = b2[i]; w3[i] = W3[i]; }
        #pragma unroll
        for (int i = 0; i < 9; ++i) w2[i] = W2[i];
        const float bb3 = b3[0];

        for (int cell = tid; cell < RB * CB; cell += 256) {
            const int rb = cell >> 6, cb = cell & 63;
            const float mean = acc_g[cell] / (cnts[rb] * cnts[64 + cb]);
            float h1[3], h2[3];
            #pragma unroll
            for (int j = 0; j < 3; ++j) h1[j] = fmaxf(mean * w1[j] + bb1[j], 0.f);
            #pragma unroll
            for (int j = 0; j < 3; ++j) {
                float v = bb2[j];
                #pragma unroll
                for (int i = 0; i < 3; ++i) v += h1[i] * w2[i * 3 + j];
                h2[j] = fmaxf(v, 0.f);
            }
            float z = bb3;
            #pragma unroll
            for (int i = 0; i < 3; ++i) z += h2[i] * w3[i];
            out[cell] = 1.0f / (1.0f + expf(-z));
        }
    }
}

extern "C" void kernel_launch(void* const* d_in, const int* in_sizes, int n_in,
                              void* d_out, int out_size, void* d_ws, size_t ws_size,
                              hipStream_t stream) {
    const float* X       = (const float*)d_in[0];
    const int*   row_ids = (const int*)  d_in[1];
    const int*   col_ids = (const int*)  d_in[2];
    const float* W1      = (const float*)d_in[3];
    const float* b1      = (const float*)d_in[4];
    const float* W2      = (const float*)d_in[5];
    const float* b2      = (const float*)d_in[6];
    const float* W3      = (const float*)d_in[7];
    const float* b3      = (const float*)d_in[8];
    float* out = (float*)d_out;

    float* acc_g  = (float*)d_ws;                 // [4096]
    float* cnts   = acc_g + RB * CB;              // [128]
    int*   ticket = (int*)(cnts + 128);           // [1]

    // ws re-poisoned to 0xAA each timed call -> zero the ~17 KB we use.
    hipMemsetAsync(d_ws, 0, (RB * CB + 128 + 16) * sizeof(float), stream);

    fused_kernel<<<GRID, 256, 0, stream>>>(X, row_ids, col_ids,
                                           acc_g, cnts, ticket,
                                           W1, b1, W2, b2, W3, b3, out);
}

// Round 4
// 375.406 us; speedup vs baseline: 1.1454x; 1.1454x over previous
//
#include <hip/hip_runtime.h>
#include <math.h>

#define NROWS 8192
#define NCOLS 8192
#define RB 64
#define CB 64

// ---------------------------------------------------------------------------
// Kernel 1 (the 268 MB stream): one pass over X -> global 64x64 block sums.
// Grid: 1024 WGs x 256 thr. WG w owns rows [(w>>3)*64,+64), cols
// [(w&7)*1024,+1024); each thread owns 4 consecutive cols (float4 loads,
// fully coalesced, 1 KiB/wave/row).
//
// row_ids sorted -> row-block id is WG-uniform and non-decreasing. Rows are
// processed in groups of 8 with a WG-uniform no-boundary fast path (8
// back-to-back dwordx4 loads in flight; only ~63 boundaries exist across all
// 128 row-chunks, so >=7/8 groups take it). On a boundary: flush register
// acc -> LDS (1 atomic/thread: the 4 cols nearly always share a col-block)
// -> <=64 global atomics into acc_g. ~2 flushes per WG total.
//
// WGs 0/1 also build the row/col histograms + cumsums (32 KB of id reads,
// hidden under the X stream of the other 1022 WGs).
// ---------------------------------------------------------------------------
__global__ __launch_bounds__(256) void fused_blocksum_kernel(
    const float* __restrict__ X,
    const int*   __restrict__ row_ids,
    const int*   __restrict__ col_ids,
    float*       __restrict__ acc_g,   // ws [4096], pre-zeroed
    float*       __restrict__ cnts,    // ws [128] fp32 counts
    float*       __restrict__ out)     // d_out (cumsums at [4096..4225])
{
    __shared__ int   rids[64];
    __shared__ float lacc[64];
    __shared__ int   hist[64];

    const int tid = threadIdx.x;
    const int bx  = blockIdx.x & 7;
    const int by  = blockIdx.x >> 3;

    // ---- counts + cumsums (WGs 0,1; block-uniform branch) ----
    if (blockIdx.x < 2) {
        const int* ids = (blockIdx.x == 0) ? row_ids : col_ids;
        const int  n   = (blockIdx.x == 0) ? NROWS : NCOLS;
        if (tid < 64) hist[tid] = 0;
        __syncthreads();
        for (int i = tid; i < n; i += 256) atomicAdd(&hist[ids[i]], 1);
        __syncthreads();
        if (tid < 64) cnts[blockIdx.x * 64 + tid] = (float)hist[tid];
        if (tid == 0) {
            float* obase = out + RB * CB + blockIdx.x * (RB + 1);
            int c = 0;
            obase[0] = 0.0f;
            for (int i = 0; i < 64; ++i) { c += hist[i]; obase[i + 1] = (float)c; }
        }
        __syncthreads();
    }

    // ---- tile reduction ----
    if (tid < 64) { rids[tid] = row_ids[by * 64 + tid]; lacc[tid] = 0.0f; }
    __syncthreads();

    const int   c     = bx * 1024 + tid * 4;
    const int4  cb4   = *(const int4*)(col_ids + c);
    const bool  split = (cb4.x != cb4.w);       // 4 cols span >1 col-block (rare)
    const float* Xp   = X + (size_t)(by * 64) * NCOLS + c;

    float4 a   = make_float4(0.f, 0.f, 0.f, 0.f);
    int    cur = rids[0];

    auto FLUSH = [&](int blk) {                 // WG-uniform call sites only
        if (split) {
            atomicAdd(&lacc[cb4.x], a.x); atomicAdd(&lacc[cb4.y], a.y);
            atomicAdd(&lacc[cb4.z], a.z); atomicAdd(&lacc[cb4.w], a.w);
        } else {
            atomicAdd(&lacc[cb4.x], a.x + a.y + a.z + a.w);
        }
        __syncthreads();
        if (tid < 64) {
            const float v = lacc[tid];
            if (v != 0.0f) atomicAdd(&acc_g[blk * 64 + tid], v);
        }
        __syncthreads();
        if (tid < 64) lacc[tid] = 0.0f;
        __syncthreads();
        a = make_float4(0.f, 0.f, 0.f, 0.f);
    };

    for (int g = 0; g < 8; ++g) {
        const int rb0 = rids[g * 8];
        if (rb0 != cur) { FLUSH(cur); cur = rb0; }        // WG-uniform
        if (rids[g * 8 + 7] == rb0) {
            // fast path: no boundary in this group -> 8 loads in flight
            #pragma unroll
            for (int j = 0; j < 8; ++j) {
                const float4 v = *(const float4*)(Xp + (size_t)(g * 8 + j) * NCOLS);
                a.x += v.x; a.y += v.y; a.z += v.z; a.w += v.w;
            }
        } else {
            for (int j = 0; j < 8; ++j) {
                const int rb = rids[g * 8 + j];
                if (rb != cur) { FLUSH(cur); cur = rb; }  // WG-uniform
                const float4 v = *(const float4*)(Xp + (size_t)(g * 8 + j) * NCOLS);
                a.x += v.x; a.y += v.y; a.z += v.z; a.w += v.w;
            }
        }
    }
    FLUSH(cur);
}

// ---------------------------------------------------------------------------
// Kernel 2 (tiny): 4096 cells, mean -> 1->3->3->1 relu MLP -> sigmoid.
// ---------------------------------------------------------------------------
__global__ __launch_bounds__(256) void mlp_kernel(
    const float* __restrict__ acc_g,
    const float* __restrict__ cnts,
    const float* __restrict__ W1, const float* __restrict__ b1,
    const float* __restrict__ W2, const float* __restrict__ b2,
    const float* __restrict__ W3, const float* __restrict__ b3,
    float*       __restrict__ out)
{
    const int cell = blockIdx.x * 256 + threadIdx.x;   // 16 WGs * 256 = 4096
    const int rb = cell >> 6, cb = cell & 63;
    const float mean = acc_g[cell] / (cnts[rb] * cnts[64 + cb]);

    float h1[3], h2[3];
    #pragma unroll
    for (int j = 0; j < 3; ++j)
        h1[j] = fmaxf(mean * W1[j] + b1[j], 0.f);
    #pragma unroll
    for (int j = 0; j < 3; ++j) {
        float v = b2[j];
        #pragma unroll
        for (int i = 0; i < 3; ++i) v += h1[i] * W2[i * 3 + j];
        h2[j] = fmaxf(v, 0.f);
    }
    float z = b3[0];
    #pragma unroll
    for (int i = 0; i < 3; ++i) z += h2[i] * W3[i];

    out[cell] = 1.0f / (1.0f + expf(-z));
}

extern "C" void kernel_launch(void* const* d_in, const int* in_sizes, int n_in,
                              void* d_out, int out_size, void* d_ws, size_t ws_size,
                              hipStream_t stream) {
    const float* X       = (const float*)d_in[0];
    const int*   row_ids = (const int*)  d_in[1];
    const int*   col_ids = (const int*)  d_in[2];
    const float* W1      = (const float*)d_in[3];
    const float* b1      = (const float*)d_in[4];
    const float* W2      = (const float*)d_in[5];
    const float* b2      = (const float*)d_in[6];
    const float* W3      = (const float*)d_in[7];
    const float* b3      = (const float*)d_in[8];
    float* out = (float*)d_out;

    float* acc_g = (float*)d_ws;              // [4096]
    float* cnts  = acc_g + RB * CB;           // [128]

    // ws re-poisoned to 0xAA each timed call -> zero the ~17 KB we use.
    hipMemsetAsync(d_ws, 0, (RB * CB + 128) * sizeof(float), stream);

    fused_blocksum_kernel<<<1024, 256, 0, stream>>>(X, row_ids, col_ids,
                                                    acc_g, cnts, out);
    mlp_kernel<<<16, 256, 0, stream>>>(acc_g, cnts,
                                       W1, b1, W2, b2, W3, b3, out);
}